// Round 3
// baseline (315.689 us; speedup 1.0000x reference)
//
#include <hip/hip_runtime.h>
#include <hip/hip_bf16.h>

#define BATCH 8
#define CH    256
#define DIM   128
#define NSP   4096   // 64*64 spatial

using bf16 = __hip_bfloat16;
typedef __attribute__((ext_vector_type(8))) short bf16x8;
typedef __attribute__((ext_vector_type(4))) float f32x4;

__device__ __forceinline__ unsigned short f2b(float f) {
  return __builtin_bit_cast(unsigned short, __float2bfloat16(f));
}

__device__ __forceinline__ void gload16(const void* g, void* l) {
  __builtin_amdgcn_global_load_lds(
      (const __attribute__((address_space(1))) unsigned int*)g,
      (__attribute__((address_space(3))) unsigned int*)l, 16, 0, 0);
}

// ---------------------------------------------------------------- weights cvt
__global__ __launch_bounds__(256) void k_weights(const float* __restrict__ Wg,
                                                 const float* __restrict__ Wt,
                                                 const float* __restrict__ Wp,
                                                 const float* __restrict__ Wm,
                                                 bf16* __restrict__ Wcat,
                                                 bf16* __restrict__ Wmb) {
  int i = blockIdx.x * 256 + threadIdx.x;
  if (i < 3 * DIM * CH) {
    const float* src = (i < 32768) ? Wg : (i < 65536 ? Wt : Wp);
    Wcat[i] = __float2bfloat16(src[i & 32767]);
  }
  if (i < CH * DIM) Wmb[i] = __float2bfloat16(Wm[i]);
}

// ------------------------------------------------- x[b][c][n] -> xbT[b][n][c]
__global__ __launch_bounds__(256) void k_transpose(const float* __restrict__ x,
                                                   bf16* __restrict__ xbT) {
  __shared__ __align__(16) float tile[64][68];
  const int b = blockIdx.z, ct = blockIdx.y, nt = blockIdx.x;
  const int t = threadIdx.x;
  const int tr = t >> 4;        // 0..15
  const int tc = t & 15;        // 0..15
  const float* src = x + ((size_t)b * CH + ct * 64) * NSP + nt * 64;
  #pragma unroll
  for (int p = 0; p < 4; ++p) {
    int c = p * 16 + tr;
    float4 v = *(const float4*)(src + (size_t)c * NSP + tc * 4);
    *(float4*)(&tile[c][tc * 4]) = v;
  }
  __syncthreads();
  bf16* dst = xbT + ((size_t)b * NSP + nt * 64) * CH + ct * 64;
  #pragma unroll
  for (int p = 0; p < 4; ++p) {
    int n = p * 16 + tr;
    ushort4 pk;
    pk.x = f2b(tile[tc * 4 + 0][n]);
    pk.y = f2b(tile[tc * 4 + 1][n]);
    pk.z = f2b(tile[tc * 4 + 2][n]);
    pk.w = f2b(tile[tc * 4 + 3][n]);
    *(ushort4*)(dst + (size_t)n * CH + tc * 4) = pk;
  }
}

// ------------------------------------- projections: D[m=out-ch][n] = W @ xbT^T
// p=0 -> gT[b][d][n], p=1 -> theta[b][n][d], p=2 -> phi[b][n][d]
__global__ __launch_bounds__(256) void k_proj(const bf16* __restrict__ Wcat,
                                              const bf16* __restrict__ xbT,
                                              const float* __restrict__ bg,
                                              const float* __restrict__ bt,
                                              const float* __restrict__ bp,
                                              bf16* __restrict__ theta,
                                              bf16* __restrict__ phi,
                                              bf16* __restrict__ gT) {
  __shared__ __align__(16) char lds[32768];
  const int b = blockIdx.z, p = blockIdx.y, nt = blockIdx.x;
  const int tid = threadIdx.x;
  const int l = tid & 63, w = tid >> 6;
  const int wm = w >> 1, wn = w & 1;
  const int lr = l & 15, lh = l >> 4;
  const int ldsw = (tid & ~63) << 4;

  f32x4 acc[4][4];
  #pragma unroll
  for (int i = 0; i < 4; ++i)
    #pragma unroll
    for (int j = 0; j < 4; ++j) acc[i][j] = (f32x4){0.f, 0.f, 0.f, 0.f};

  const bf16* Asrc = Wcat + (size_t)p * DIM * CH;
  const bf16* Bsrc = xbT + ((size_t)b * NSP + nt * 128) * CH;

  for (int kt = 0; kt < 4; ++kt) {
    const int k0 = kt * 64;
    #pragma unroll
    for (int cc = 0; cc < 4; ++cc) {
      int t = cc * 256 + tid;
      int row = t >> 3, g = t & 7;
      gload16(Asrc + (size_t)row * CH + k0 + ((g ^ (row & 7)) << 3),
              lds + cc * 4096 + ldsw);
      gload16(Bsrc + (size_t)row * CH + k0 + ((g ^ (row & 7)) << 3),
              lds + 16384 + cc * 4096 + ldsw);
    }
    __syncthreads();
    #pragma unroll
    for (int kk = 0; kk < 2; ++kk) {
      bf16x8 af[4], bfr[4];
      #pragma unroll
      for (int mf = 0; mf < 4; ++mf) {
        int row = wm * 64 + mf * 16 + lr;
        int g = kk * 4 + lh;
        af[mf] = *(const bf16x8*)(lds + row * 128 + ((g ^ (row & 7)) << 4));
      }
      #pragma unroll
      for (int nf = 0; nf < 4; ++nf) {
        int row = wn * 64 + nf * 16 + lr;
        int g = kk * 4 + lh;
        bfr[nf] = *(const bf16x8*)(lds + 16384 + row * 128 + ((g ^ (row & 7)) << 4));
      }
      #pragma unroll
      for (int mf = 0; mf < 4; ++mf)
        #pragma unroll
        for (int nf = 0; nf < 4; ++nf)
          acc[mf][nf] = __builtin_amdgcn_mfma_f32_16x16x32_bf16(af[mf], bfr[nf],
                                                                acc[mf][nf], 0, 0, 0);
    }
    __syncthreads();
  }

  const float* bias = (p == 0) ? bg : (p == 1 ? bt : bp);
  bf16* nd = (p == 1) ? theta : phi;
  #pragma unroll
  for (int mf = 0; mf < 4; ++mf) {
    const int dbase = wm * 64 + mf * 16 + lh * 4;
    const float4 bv = *(const float4*)(bias + dbase);
    float bvv[4] = {bv.x, bv.y, bv.z, bv.w};
    #pragma unroll
    for (int nf = 0; nf < 4; ++nf) {
      const int n = nt * 128 + wn * 64 + nf * 16 + lr;
      float v[4];
      #pragma unroll
      for (int r = 0; r < 4; ++r) v[r] = acc[mf][nf][r] + bvv[r];
      if (p == 0) {
        #pragma unroll
        for (int r = 0; r < 4; ++r)
          gT[((size_t)b * DIM + dbase + r) * NSP + n] = __float2bfloat16(v[r]);
      } else {
        ushort4 pk;
        pk.x = f2b(v[0]); pk.y = f2b(v[1]); pk.z = f2b(v[2]); pk.w = f2b(v[3]);
        *(ushort4*)(nd + ((size_t)b * NSP + n) * DIM + dbase) = pk;
      }
    }
  }
}

// --------------------------------------------------------- flash attention
// Q=theta[b][n][d], K=phi[b][n][d], V=gT[b][d][n]; y[b][n][d] = softmax(QK^T)V
__global__ __launch_bounds__(256) void k_attn(const bf16* __restrict__ theta,
                                              const bf16* __restrict__ phi,
                                              const bf16* __restrict__ gT,
                                              bf16* __restrict__ y) {
  __shared__ __align__(16) char lds[40960];   // K 16K | Vt 16K | P 4*2K
  const int b = blockIdx.y, qt = blockIdx.x;
  const int tid = threadIdx.x;
  const int l = tid & 63, w = tid >> 6;
  const int lr = l & 15, lh = l >> 4;
  const int ldsw = (tid & ~63) << 4;

  bf16x8 qf[4];
  {
    const bf16* qsrc =
        theta + ((size_t)(b * NSP + qt * 64 + w * 16 + lr)) * DIM + lh * 8;
    #pragma unroll
    for (int f = 0; f < 4; ++f) qf[f] = *(const bf16x8*)(qsrc + f * 32);
  }

  f32x4 o[8];
  #pragma unroll
  for (int dt = 0; dt < 8; ++dt) o[dt] = (f32x4){0.f, 0.f, 0.f, 0.f};
  float m[4] = {-INFINITY, -INFINITY, -INFINITY, -INFINITY};
  float s[4] = {0.f, 0.f, 0.f, 0.f};

  const bf16* Ksrc = phi + (size_t)b * NSP * DIM;
  const bf16* Vsrc = gT + (size_t)b * DIM * NSP;

  for (int it = 0; it < 64; ++it) {
    const int kv0 = it * 64;
    #pragma unroll
    for (int cc = 0; cc < 4; ++cc) {           // K tile [64 kv][128 d]
      int t = cc * 256 + tid;
      int row = t >> 4, g = t & 15;
      gload16(Ksrc + (size_t)(kv0 + row) * DIM + ((g ^ (row & 7)) << 3),
              lds + cc * 4096 + ldsw);
    }
    #pragma unroll
    for (int cc = 0; cc < 4; ++cc) {           // Vt tile [128 d][64 kv]
      int t = cc * 256 + tid;
      int row = t >> 3, g = t & 7;
      gload16(Vsrc + (size_t)row * NSP + kv0 + ((g ^ (row & 7)) << 3),
              lds + 16384 + cc * 4096 + ldsw);
    }
    __syncthreads();

    // S = Q @ K^T  (16q x 64kv per wave)
    f32x4 sa[4];
    #pragma unroll
    for (int ct = 0; ct < 4; ++ct) sa[ct] = (f32x4){0.f, 0.f, 0.f, 0.f};
    #pragma unroll
    for (int ct = 0; ct < 4; ++ct) {
      const int row = ct * 16 + lr;
      #pragma unroll
      for (int f = 0; f < 4; ++f) {
        const int g = f * 4 + lh;
        bf16x8 kf = *(const bf16x8*)(lds + row * 256 + ((g ^ (row & 7)) << 4));
        sa[ct] = __builtin_amdgcn_mfma_f32_16x16x32_bf16(qf[f], kf, sa[ct], 0, 0, 0);
      }
    }

    // online softmax (rows q = lh*4+r; reduce across the 16 lanes of lr)
    float scale[4];
    #pragma unroll
    for (int r = 0; r < 4; ++r) {
      float mx = fmaxf(fmaxf(sa[0][r], sa[1][r]), fmaxf(sa[2][r], sa[3][r]));
      mx = fmaxf(mx, __shfl_xor(mx, 1));
      mx = fmaxf(mx, __shfl_xor(mx, 2));
      mx = fmaxf(mx, __shfl_xor(mx, 4));
      mx = fmaxf(mx, __shfl_xor(mx, 8));
      const float mt = fmaxf(m[r], mx);
      scale[r] = __expf(m[r] - mt);
      m[r] = mt;
      float rs = 0.f;
      #pragma unroll
      for (int ct = 0; ct < 4; ++ct) {
        sa[ct][r] = __expf(sa[ct][r] - mt);
        rs += sa[ct][r];
      }
      rs += __shfl_xor(rs, 1);
      rs += __shfl_xor(rs, 2);
      rs += __shfl_xor(rs, 4);
      rs += __shfl_xor(rs, 8);
      s[r] = s[r] * scale[r] + rs;
    }
    #pragma unroll
    for (int dt = 0; dt < 8; ++dt)
      #pragma unroll
      for (int r = 0; r < 4; ++r) o[dt][r] *= scale[r];

    // P -> per-wave LDS (swizzled), then re-fragment as PV's A operand
    #pragma unroll
    for (int ct = 0; ct < 4; ++ct)
      #pragma unroll
      for (int r = 0; r < 4; ++r) {
        const int q = lh * 4 + r;
        const int col = ct * 16 + lr;
        const int gc = col >> 3;
        *(unsigned short*)(lds + 32768 + w * 2048 + q * 128 +
                           ((gc ^ (q & 7)) << 4) + (col & 7) * 2) = f2b(sa[ct][r]);
      }
    asm volatile("s_waitcnt lgkmcnt(0)" ::: "memory");

    #pragma unroll
    for (int kt = 0; kt < 2; ++kt) {
      const int gp = kt * 4 + lh;
      bf16x8 pf = *(const bf16x8*)(lds + 32768 + w * 2048 + lr * 128 +
                                   ((gp ^ (lr & 7)) << 4));
      #pragma unroll
      for (int dt = 0; dt < 8; ++dt) {
        const int row = dt * 16 + lr;
        bf16x8 vf = *(const bf16x8*)(lds + 16384 + row * 128 + ((gp ^ (row & 7)) << 4));
        o[dt] = __builtin_amdgcn_mfma_f32_16x16x32_bf16(pf, vf, o[dt], 0, 0, 0);
      }
    }
    __syncthreads();
  }

  #pragma unroll
  for (int dt = 0; dt < 8; ++dt) {
    const int d = dt * 16 + lr;
    #pragma unroll
    for (int r = 0; r < 4; ++r) {
      const int q = qt * 64 + w * 16 + lh * 4 + r;
      y[(size_t)(b * NSP + q) * DIM + d] = __float2bfloat16(o[dt][r] / s[r]);
    }
  }
}

// ------------------------------------- out = Wm @ y^T + bm + x  (fp32 output)
__global__ __launch_bounds__(256) void k_final(const bf16* __restrict__ Wmb,
                                               const bf16* __restrict__ yb,
                                               const float* __restrict__ bm,
                                               const float* __restrict__ x,
                                               float* __restrict__ out) {
  __shared__ __align__(16) char lds[32768];
  const int b = blockIdx.z, mt = blockIdx.y, nt = blockIdx.x;
  const int tid = threadIdx.x;
  const int l = tid & 63, w = tid >> 6;
  const int wm = w >> 1, wn = w & 1;
  const int lr = l & 15, lh = l >> 4;
  const int ldsw = (tid & ~63) << 4;

  f32x4 acc[4][4];
  #pragma unroll
  for (int i = 0; i < 4; ++i)
    #pragma unroll
    for (int j = 0; j < 4; ++j) acc[i][j] = (f32x4){0.f, 0.f, 0.f, 0.f};

  const bf16* Asrc = Wmb + (size_t)mt * 128 * DIM;
  const bf16* Bsrc = yb + ((size_t)b * NSP + nt * 128) * DIM;

  for (int kt = 0; kt < 2; ++kt) {
    const int k0 = kt * 64;
    #pragma unroll
    for (int cc = 0; cc < 4; ++cc) {
      int t = cc * 256 + tid;
      int row = t >> 3, g = t & 7;
      gload16(Asrc + (size_t)row * DIM + k0 + ((g ^ (row & 7)) << 3),
              lds + cc * 4096 + ldsw);
      gload16(Bsrc + (size_t)row * DIM + k0 + ((g ^ (row & 7)) << 3),
              lds + 16384 + cc * 4096 + ldsw);
    }
    __syncthreads();
    #pragma unroll
    for (int kk = 0; kk < 2; ++kk) {
      bf16x8 af[4], bfr[4];
      #pragma unroll
      for (int mf = 0; mf < 4; ++mf) {
        int row = wm * 64 + mf * 16 + lr;
        int g = kk * 4 + lh;
        af[mf] = *(const bf16x8*)(lds + row * 128 + ((g ^ (row & 7)) << 4));
      }
      #pragma unroll
      for (int nf = 0; nf < 4; ++nf) {
        int row = wn * 64 + nf * 16 + lr;
        int g = kk * 4 + lh;
        bfr[nf] = *(const bf16x8*)(lds + 16384 + row * 128 + ((g ^ (row & 7)) << 4));
      }
      #pragma unroll
      for (int mf = 0; mf < 4; ++mf)
        #pragma unroll
        for (int nf = 0; nf < 4; ++nf)
          acc[mf][nf] = __builtin_amdgcn_mfma_f32_16x16x32_bf16(af[mf], bfr[nf],
                                                                acc[mf][nf], 0, 0, 0);
    }
    __syncthreads();
  }

  #pragma unroll
  for (int mf = 0; mf < 4; ++mf) {
    const int cbase = mt * 128 + wm * 64 + mf * 16 + lh * 4;
    const float4 bv = *(const float4*)(bm + cbase);
    float bvv[4] = {bv.x, bv.y, bv.z, bv.w};
    #pragma unroll
    for (int nf = 0; nf < 4; ++nf) {
      const int n = nt * 128 + wn * 64 + nf * 16 + lr;
      #pragma unroll
      for (int r = 0; r < 4; ++r) {
        const size_t idx = ((size_t)b * CH + cbase + r) * NSP + n;
        out[idx] = acc[mf][nf][r] + bvv[r] + x[idx];
      }
    }
  }
}

// ---------------------------------------------------------------------- launch
extern "C" void kernel_launch(void* const* d_in, const int* in_sizes, int n_in,
                              void* d_out, int out_size, void* d_ws, size_t ws_size,
                              hipStream_t stream) {
  const float* x  = (const float*)d_in[0];
  const float* Wg = (const float*)d_in[1];
  const float* bg = (const float*)d_in[2];
  const float* Wt = (const float*)d_in[3];
  const float* bt = (const float*)d_in[4];
  const float* Wp = (const float*)d_in[5];
  const float* bp = (const float*)d_in[6];
  const float* Wm = (const float*)d_in[7];
  const float* bm = (const float*)d_in[8];
  float* out = (float*)d_out;
  char* ws = (char*)d_ws;

  // workspace layout (bytes) — total 50,593,792
  bf16* xbT   = (bf16*)(ws + 0);           // [B][N][C]   16,777,216
  bf16* Wcat  = (bf16*)(ws + 16777216);    // [384][256]     196,608
  bf16* Wmb   = (bf16*)(ws + 16973824);    // [256][128]      65,536
  bf16* theta = (bf16*)(ws + 17039360);    // [B][N][128]  8,388,608
  bf16* phi   = (bf16*)(ws + 25427968);    // [B][N][128]  8,388,608
  bf16* gT    = (bf16*)(ws + 33816576);    // [B][128][N]  8,388,608
  bf16* yb    = (bf16*)(ws + 42205184);    // [B][N][128]  8,388,608

  k_weights  <<<dim3(384),       dim3(256), 0, stream>>>(Wg, Wt, Wp, Wm, Wcat, Wmb);
  k_transpose<<<dim3(64, 4, 8),  dim3(256), 0, stream>>>(x, xbT);
  k_proj     <<<dim3(32, 3, 8),  dim3(256), 0, stream>>>(Wcat, xbT, bg, bt, bp,
                                                         theta, phi, gT);
  k_attn     <<<dim3(64, 8),     dim3(256), 0, stream>>>(theta, phi, gT, yb);
  k_final    <<<dim3(32, 2, 8),  dim3(256), 0, stream>>>(Wmb, yb, bm, x, out);
}

// Round 4
// 259.612 us; speedup vs baseline: 1.2160x; 1.2160x over previous
//
#include <hip/hip_runtime.h>
#include <hip/hip_bf16.h>

#define BATCH 8
#define CH    256
#define DIM   128
#define NSP   4096   // 64*64 spatial

using bf16 = __hip_bfloat16;
typedef __attribute__((ext_vector_type(8))) short bf16x8;
typedef __attribute__((ext_vector_type(4))) float f32x4;

__device__ __forceinline__ unsigned short f2b(float f) {
  return __builtin_bit_cast(unsigned short, __float2bfloat16(f));
}

__device__ __forceinline__ void gload16(const void* g, void* l) {
  __builtin_amdgcn_global_load_lds(
      (const __attribute__((address_space(1))) unsigned int*)g,
      (__attribute__((address_space(3))) unsigned int*)l, 16, 0, 0);
}

// ---------------------------------------------------------------- weights cvt
__global__ __launch_bounds__(256) void k_weights(const float* __restrict__ Wg,
                                                 const float* __restrict__ Wt,
                                                 const float* __restrict__ Wp,
                                                 const float* __restrict__ Wm,
                                                 bf16* __restrict__ Wcat,
                                                 bf16* __restrict__ Wmb) {
  int i = blockIdx.x * 256 + threadIdx.x;
  if (i < 3 * DIM * CH) {
    const float* src = (i < 32768) ? Wg : (i < 65536 ? Wt : Wp);
    Wcat[i] = __float2bfloat16(src[i & 32767]);
  }
  if (i < CH * DIM) Wmb[i] = __float2bfloat16(Wm[i]);
}

// ------------------------------------------------- x[b][c][n] -> xbT[b][n][c]
__global__ __launch_bounds__(256) void k_transpose(const float* __restrict__ x,
                                                   bf16* __restrict__ xbT) {
  __shared__ __align__(16) float tile[64][68];
  const int b = blockIdx.z, ct = blockIdx.y, nt = blockIdx.x;
  const int t = threadIdx.x;
  const int tr = t >> 4;        // 0..15
  const int tc = t & 15;        // 0..15
  const float* src = x + ((size_t)b * CH + ct * 64) * NSP + nt * 64;
  #pragma unroll
  for (int p = 0; p < 4; ++p) {
    int c = p * 16 + tr;
    float4 v = *(const float4*)(src + (size_t)c * NSP + tc * 4);
    *(float4*)(&tile[c][tc * 4]) = v;
  }
  __syncthreads();
  bf16* dst = xbT + ((size_t)b * NSP + nt * 64) * CH + ct * 64;
  #pragma unroll
  for (int p = 0; p < 4; ++p) {
    int n = p * 16 + tr;
    ushort4 pk;
    pk.x = f2b(tile[tc * 4 + 0][n]);
    pk.y = f2b(tile[tc * 4 + 1][n]);
    pk.z = f2b(tile[tc * 4 + 2][n]);
    pk.w = f2b(tile[tc * 4 + 3][n]);
    *(ushort4*)(dst + (size_t)n * CH + tc * 4) = pk;
  }
}

// ------------------------------------- projections: D[m=out-ch][n] = W @ xbT^T
// p=0 -> gT[b][d][n], p=1 -> theta[b][n][d], p=2 -> phi[b][n][d]
__global__ __launch_bounds__(256) void k_proj(const bf16* __restrict__ Wcat,
                                              const bf16* __restrict__ xbT,
                                              const float* __restrict__ bg,
                                              const float* __restrict__ bt,
                                              const float* __restrict__ bp,
                                              bf16* __restrict__ theta,
                                              bf16* __restrict__ phi,
                                              bf16* __restrict__ gT) {
  __shared__ __align__(16) char lds[32768];
  const int b = blockIdx.z, p = blockIdx.y, nt = blockIdx.x;
  const int tid = threadIdx.x;
  const int l = tid & 63, w = tid >> 6;
  const int wm = w >> 1, wn = w & 1;
  const int lr = l & 15, lh = l >> 4;
  const int ldsw = (tid & ~63) << 4;

  f32x4 acc[4][4];
  #pragma unroll
  for (int i = 0; i < 4; ++i)
    #pragma unroll
    for (int j = 0; j < 4; ++j) acc[i][j] = (f32x4){0.f, 0.f, 0.f, 0.f};

  const bf16* Asrc = Wcat + (size_t)p * DIM * CH;
  const bf16* Bsrc = xbT + ((size_t)b * NSP + nt * 128) * CH;

  for (int kt = 0; kt < 4; ++kt) {
    const int k0 = kt * 64;
    #pragma unroll
    for (int cc = 0; cc < 4; ++cc) {
      int t = cc * 256 + tid;
      int row = t >> 3, g = t & 7;
      gload16(Asrc + (size_t)row * CH + k0 + ((g ^ (row & 7)) << 3),
              lds + cc * 4096 + ldsw);
      gload16(Bsrc + (size_t)row * CH + k0 + ((g ^ (row & 7)) << 3),
              lds + 16384 + cc * 4096 + ldsw);
    }
    __syncthreads();
    #pragma unroll
    for (int kk = 0; kk < 2; ++kk) {
      bf16x8 af[4], bfr[4];
      #pragma unroll
      for (int mf = 0; mf < 4; ++mf) {
        int row = wm * 64 + mf * 16 + lr;
        int g = kk * 4 + lh;
        af[mf] = *(const bf16x8*)(lds + row * 128 + ((g ^ (row & 7)) << 4));
      }
      #pragma unroll
      for (int nf = 0; nf < 4; ++nf) {
        int row = wn * 64 + nf * 16 + lr;
        int g = kk * 4 + lh;
        bfr[nf] = *(const bf16x8*)(lds + 16384 + row * 128 + ((g ^ (row & 7)) << 4));
      }
      #pragma unroll
      for (int mf = 0; mf < 4; ++mf)
        #pragma unroll
        for (int nf = 0; nf < 4; ++nf)
          acc[mf][nf] = __builtin_amdgcn_mfma_f32_16x16x32_bf16(af[mf], bfr[nf],
                                                                acc[mf][nf], 0, 0, 0);
    }
    __syncthreads();
  }

  const float* bias = (p == 0) ? bg : (p == 1 ? bt : bp);
  bf16* nd = (p == 1) ? theta : phi;
  #pragma unroll
  for (int mf = 0; mf < 4; ++mf) {
    const int dbase = wm * 64 + mf * 16 + lh * 4;
    const float4 bv = *(const float4*)(bias + dbase);
    float bvv[4] = {bv.x, bv.y, bv.z, bv.w};
    #pragma unroll
    for (int nf = 0; nf < 4; ++nf) {
      const int n = nt * 128 + wn * 64 + nf * 16 + lr;
      float v[4];
      #pragma unroll
      for (int r = 0; r < 4; ++r) v[r] = acc[mf][nf][r] + bvv[r];
      if (p == 0) {
        #pragma unroll
        for (int r = 0; r < 4; ++r)
          gT[((size_t)b * DIM + dbase + r) * NSP + n] = __float2bfloat16(v[r]);
      } else {
        ushort4 pk;
        pk.x = f2b(v[0]); pk.y = f2b(v[1]); pk.z = f2b(v[2]); pk.w = f2b(v[3]);
        *(ushort4*)(nd + ((size_t)b * NSP + n) * DIM + dbase) = pk;
      }
    }
  }
}

// --------------------------------------------------------- flash attention
// Q=theta[b][n][d], K=phi[b][n][d], V=gT[b][d][n]; y[b][n][d] = softmax(QK^T)V
// Swapped QK^T: S = mfma(K,Q) -> lane holds S[kv][q=lane&15].
// K rows sigma-permuted at staging (kv -> LDS row) so each lane's 16 S values
// are kv in {8h..8h+7} u {32+8h..32+8h+7}  (h = lane>>4) => PV A-frag in-lane.
// 2-phase double-buffered staging, raw barriers + counted vmcnt (no drain).
__global__ __launch_bounds__(256) void k_attn(const bf16* __restrict__ theta,
                                              const bf16* __restrict__ phi,
                                              const bf16* __restrict__ gT,
                                              bf16* __restrict__ y) {
  __shared__ __align__(16) char lds[65536];   // K0|K1 (2x16K) | V0|V1 (2x16K)
  const int b = blockIdx.y, qt = blockIdx.x;
  const int tid = threadIdx.x;
  const int l = tid & 63, w = tid >> 6;
  const int lr = l & 15, lh = l >> 4;
  const int ldsw = (tid & ~63) << 4;          // wave-uniform 1KB slot

  // Q fragment (B operand): q = lane&15, k-slice d = f*32 + lh*8 + j
  bf16x8 qf[4];
  {
    const bf16* qsrc =
        theta + ((size_t)(b * NSP + qt * 64 + w * 16 + lr)) * DIM + lh * 8;
    #pragma unroll
    for (int f = 0; f < 4; ++f) qf[f] = *(const bf16x8*)(qsrc + f * 32);
  }

  f32x4 o[8];
  #pragma unroll
  for (int dt = 0; dt < 8; ++dt) o[dt] = (f32x4){0.f, 0.f, 0.f, 0.f};
  float m = -INFINITY, s = 0.f;               // per-lane, for q = lane&15

  const bf16* Ksrc = phi + (size_t)b * NSP * DIM;
  const bf16* Vsrc = gT + (size_t)b * DIM * NSP;

  // stage one K/V tile into buffer `buf` (linear LDS dest; per-lane swizzled src)
  auto stage = [&](int buf, int kv0) {
    #pragma unroll
    for (int cc = 0; cc < 4; ++cc) {
      // K tile: LDS row = sigma(kv); row bits (5,4,3,2,1,0) <- kv bits (5,2,4,3,1,0)
      int t = cc * 256 + tid;
      int row = t >> 4, g = t & 15;
      int kvs = (row & 32) | (((row >> 2) & 3) << 3) | (((row >> 4) & 1) << 2) |
                (row & 3);
      gload16(Ksrc + (size_t)(kv0 + kvs) * DIM + ((g ^ (row & 7)) << 3),
              lds + buf * 16384 + cc * 4096 + ldsw);
      // Vt tile [128 d][64 kv]
      int row2 = t >> 3, g2 = t & 7;
      gload16(Vsrc + (size_t)row2 * NSP + kv0 + ((g2 ^ (row2 & 7)) << 3),
              lds + 32768 + buf * 16384 + cc * 4096 + ldsw);
    }
  };

  stage(0, 0);

  for (int it = 0; it < 64; ++it) {
    if (it < 63) {
      stage((it + 1) & 1, (it + 1) * 64);
      asm volatile("s_waitcnt vmcnt(8)" ::: "memory");   // tile `it` landed
    } else {
      asm volatile("s_waitcnt vmcnt(0)" ::: "memory");
    }
    __builtin_amdgcn_s_barrier();
    __builtin_amdgcn_sched_barrier(0);

    const char* Kb = lds + (it & 1) * 16384;
    const char* Vb = lds + 32768 + (it & 1) * 16384;

    // S^T = K @ Q^T : D[row=sigma-kv][col=q]
    f32x4 sa[4];
    #pragma unroll
    for (int ct = 0; ct < 4; ++ct) sa[ct] = (f32x4){0.f, 0.f, 0.f, 0.f};
    #pragma unroll
    for (int ct = 0; ct < 4; ++ct) {
      const int row = ct * 16 + lr;
      #pragma unroll
      for (int f = 0; f < 4; ++f) {
        const int g = f * 4 + lh;
        bf16x8 kf = *(const bf16x8*)(Kb + row * 256 + ((g ^ (row & 7)) << 4));
        sa[ct] = __builtin_amdgcn_mfma_f32_16x16x32_bf16(kf, qf[f], sa[ct], 0, 0, 0);
      }
    }
    // lane's 16 values: kv = 32*(ct>>1) + 8*lh + 4*(ct&1) + r, all for q=lane&15

    // online softmax: in-lane 16-max + 2 shuffles (lanes l, l^16, l^32, l^48 share q)
    float mx = fmaxf(fmaxf(fmaxf(sa[0][0], sa[0][1]), fmaxf(sa[0][2], sa[0][3])),
                     fmaxf(fmaxf(sa[1][0], sa[1][1]), fmaxf(sa[1][2], sa[1][3])));
    mx = fmaxf(mx,
               fmaxf(fmaxf(fmaxf(sa[2][0], sa[2][1]), fmaxf(sa[2][2], sa[2][3])),
                     fmaxf(fmaxf(sa[3][0], sa[3][1]), fmaxf(sa[3][2], sa[3][3]))));
    mx = fmaxf(mx, __shfl_xor(mx, 16));
    mx = fmaxf(mx, __shfl_xor(mx, 32));
    const float mt = fmaxf(m, mx);
    const float sc = __expf(m - mt);
    m = mt;
    float rs = 0.f;
    #pragma unroll
    for (int ct = 0; ct < 4; ++ct)
      #pragma unroll
      for (int r = 0; r < 4; ++r) {
        sa[ct][r] = __expf(sa[ct][r] - mt);
        rs += sa[ct][r];
      }
    rs += __shfl_xor(rs, 16);
    rs += __shfl_xor(rs, 32);
    s = s * sc + rs;

    // broadcast scale to o's row layout (o rows are q = 4*lh + r)
    float osc[4];
    #pragma unroll
    for (int r = 0; r < 4; ++r) osc[r] = __shfl(sc, (l & 48) | (lh * 4 + r));
    #pragma unroll
    for (int dt = 0; dt < 8; ++dt)
      #pragma unroll
      for (int r = 0; r < 4; ++r) o[dt][r] *= osc[r];

    // P fragments fully in-lane: frag[c][j] = exp-S[ct=2c+(j>>2)][r=j&3]
    bf16x8 pf[2];
    #pragma unroll
    for (int c = 0; c < 2; ++c) {
      union { bf16x8 v; unsigned short u[8]; } pw;
      #pragma unroll
      for (int u = 0; u < 2; ++u)
        #pragma unroll
        for (int r = 0; r < 4; ++r) pw.u[u * 4 + r] = f2b(sa[2 * c + u][r]);
      pf[c] = pw.v;
    }

    // PV: o[dt] += P[q][kv-chunk c] * Vt[d][kv]
    #pragma unroll
    for (int c = 0; c < 2; ++c) {
      const int gp = c * 4 + lh;
      #pragma unroll
      for (int dt = 0; dt < 8; ++dt) {
        const int row = dt * 16 + lr;
        bf16x8 vf = *(const bf16x8*)(Vb + row * 128 + ((gp ^ (row & 7)) << 4));
        o[dt] = __builtin_amdgcn_mfma_f32_16x16x32_bf16(pf[c], vf, o[dt], 0, 0, 0);
      }
    }

    asm volatile("s_waitcnt lgkmcnt(0)" ::: "memory");   // reads retired
    __builtin_amdgcn_s_barrier();                        // buffer reuse safe
  }

  // epilogue: s lives at q=lane&15; o rows are q = 4*lh + r
  float si[4];
  #pragma unroll
  for (int r = 0; r < 4; ++r) si[r] = __shfl(s, (l & 48) | (lh * 4 + r));
  #pragma unroll
  for (int dt = 0; dt < 8; ++dt) {
    const int d = dt * 16 + lr;
    #pragma unroll
    for (int r = 0; r < 4; ++r) {
      const int q = qt * 64 + w * 16 + lh * 4 + r;
      y[(size_t)(b * NSP + q) * DIM + d] = __float2bfloat16(o[dt][r] / si[r]);
    }
  }
}

// ------------------------------------- out = Wm @ y^T + bm + x  (fp32 output)
__global__ __launch_bounds__(256) void k_final(const bf16* __restrict__ Wmb,
                                               const bf16* __restrict__ yb,
                                               const float* __restrict__ bm,
                                               const float* __restrict__ x,
                                               float* __restrict__ out) {
  __shared__ __align__(16) char lds[32768];
  const int b = blockIdx.z, mt = blockIdx.y, nt = blockIdx.x;
  const int tid = threadIdx.x;
  const int l = tid & 63, w = tid >> 6;
  const int wm = w >> 1, wn = w & 1;
  const int lr = l & 15, lh = l >> 4;
  const int ldsw = (tid & ~63) << 4;

  f32x4 acc[4][4];
  #pragma unroll
  for (int i = 0; i < 4; ++i)
    #pragma unroll
    for (int j = 0; j < 4; ++j) acc[i][j] = (f32x4){0.f, 0.f, 0.f, 0.f};

  const bf16* Asrc = Wmb + (size_t)mt * 128 * DIM;
  const bf16* Bsrc = yb + ((size_t)b * NSP + nt * 128) * DIM;

  for (int kt = 0; kt < 2; ++kt) {
    const int k0 = kt * 64;
    #pragma unroll
    for (int cc = 0; cc < 4; ++cc) {
      int t = cc * 256 + tid;
      int row = t >> 3, g = t & 7;
      gload16(Asrc + (size_t)row * DIM + k0 + ((g ^ (row & 7)) << 3),
              lds + cc * 4096 + ldsw);
      gload16(Bsrc + (size_t)row * DIM + k0 + ((g ^ (row & 7)) << 3),
              lds + 16384 + cc * 4096 + ldsw);
    }
    __syncthreads();
    #pragma unroll
    for (int kk = 0; kk < 2; ++kk) {
      bf16x8 af[4], bfr[4];
      #pragma unroll
      for (int mf = 0; mf < 4; ++mf) {
        int row = wm * 64 + mf * 16 + lr;
        int g = kk * 4 + lh;
        af[mf] = *(const bf16x8*)(lds + row * 128 + ((g ^ (row & 7)) << 4));
      }
      #pragma unroll
      for (int nf = 0; nf < 4; ++nf) {
        int row = wn * 64 + nf * 16 + lr;
        int g = kk * 4 + lh;
        bfr[nf] = *(const bf16x8*)(lds + 16384 + row * 128 + ((g ^ (row & 7)) << 4));
      }
      #pragma unroll
      for (int mf = 0; mf < 4; ++mf)
        #pragma unroll
        for (int nf = 0; nf < 4; ++nf)
          acc[mf][nf] = __builtin_amdgcn_mfma_f32_16x16x32_bf16(af[mf], bfr[nf],
                                                                acc[mf][nf], 0, 0, 0);
    }
    __syncthreads();
  }

  #pragma unroll
  for (int mf = 0; mf < 4; ++mf) {
    const int cbase = mt * 128 + wm * 64 + mf * 16 + lh * 4;
    const float4 bv = *(const float4*)(bm + cbase);
    float bvv[4] = {bv.x, bv.y, bv.z, bv.w};
    #pragma unroll
    for (int nf = 0; nf < 4; ++nf) {
      const int n = nt * 128 + wn * 64 + nf * 16 + lr;
      #pragma unroll
      for (int r = 0; r < 4; ++r) {
        const size_t idx = ((size_t)b * CH + cbase + r) * NSP + n;
        out[idx] = acc[mf][nf][r] + bvv[r] + x[idx];
      }
    }
  }
}

// ---------------------------------------------------------------------- launch
extern "C" void kernel_launch(void* const* d_in, const int* in_sizes, int n_in,
                              void* d_out, int out_size, void* d_ws, size_t ws_size,
                              hipStream_t stream) {
  const float* x  = (const float*)d_in[0];
  const float* Wg = (const float*)d_in[1];
  const float* bg = (const float*)d_in[2];
  const float* Wt = (const float*)d_in[3];
  const float* bt = (const float*)d_in[4];
  const float* Wp = (const float*)d_in[5];
  const float* bp = (const float*)d_in[6];
  const float* Wm = (const float*)d_in[7];
  const float* bm = (const float*)d_in[8];
  float* out = (float*)d_out;
  char* ws = (char*)d_ws;

  // workspace layout (bytes) — total 50,593,792
  bf16* xbT   = (bf16*)(ws + 0);           // [B][N][C]   16,777,216
  bf16* Wcat  = (bf16*)(ws + 16777216);    // [384][256]     196,608
  bf16* Wmb   = (bf16*)(ws + 16973824);    // [256][128]      65,536
  bf16* theta = (bf16*)(ws + 17039360);    // [B][N][128]  8,388,608
  bf16* phi   = (bf16*)(ws + 25427968);    // [B][N][128]  8,388,608
  bf16* gT    = (bf16*)(ws + 33816576);    // [B][128][N]  8,388,608
  bf16* yb    = (bf16*)(ws + 42205184);    // [B][N][128]  8,388,608

  k_weights  <<<dim3(384),       dim3(256), 0, stream>>>(Wg, Wt, Wp, Wm, Wcat, Wmb);
  k_transpose<<<dim3(64, 4, 8),  dim3(256), 0, stream>>>(x, xbT);
  k_proj     <<<dim3(32, 3, 8),  dim3(256), 0, stream>>>(Wcat, xbT, bg, bt, bp,
                                                         theta, phi, gT);
  k_attn     <<<dim3(64, 8),     dim3(256), 0, stream>>>(theta, phi, gT, yb);
  k_final    <<<dim3(32, 2, 8),  dim3(256), 0, stream>>>(Wmb, yb, bm, x, out);
}